// Round 4
// baseline (673.796 us; speedup 1.0000x reference)
//
#include <hip/hip_runtime.h>
#include <hip/hip_bf16.h>

#define HDD 64
#define NH 16
#define SEQ 2048
#define DM 1024
#define BB 4

using bf16x8 = __attribute__((ext_vector_type(8))) short;
using floatx4 = __attribute__((ext_vector_type(4))) float;

__device__ __forceinline__ short f2bf(float f) {
    __hip_bfloat16 h = __float2bfloat16(f);
    union { __hip_bfloat16 h; short s; } c;
    c.h = h;
    return c.s;
}

// Stage 8 contiguous fp32 elements from global into LDS as bf16.
__device__ __forceinline__ void stage8f(short* dst, const float* s) {
    float4 a = *(const float4*)s;
    float4 b = *(const float4*)(s + 4);
    bf16x8 r;
    r[0] = f2bf(a.x); r[1] = f2bf(a.y); r[2] = f2bf(a.z); r[3] = f2bf(a.w);
    r[4] = f2bf(b.x); r[5] = f2bf(b.y); r[6] = f2bf(b.z); r[7] = f2bf(b.w);
    *(bf16x8*)dst = r;
}

// ---------------------------------------------------------------------------
// QKV projection: Y = X @ W^T + b (fp32 in, bf16 MFMA), written head-split
// as [B,H,S,HD] bf16 into ws. 128x128 tile, 4 waves, LDS stride 40.
// ---------------------------------------------------------------------------
__global__ __launch_bounds__(256) void proj_kernel(
    const float* __restrict__ q, const float* __restrict__ k, const float* __restrict__ v,
    const float* __restrict__ wq, const float* __restrict__ bq,
    const float* __restrict__ wk, const float* __restrict__ bk,
    const float* __restrict__ wv, const float* __restrict__ bv,
    short* __restrict__ Qh, short* __restrict__ Kh, short* __restrict__ Vh)
{
    const int z = blockIdx.z;
    const float* X  = (z == 0) ? q  : (z == 1) ? k  : v;
    const float* W  = (z == 0) ? wq : (z == 1) ? wk : wv;
    const float* Bp = (z == 0) ? bq : (z == 1) ? bk : bv;
    short* Dst      = (z == 0) ? Qh : (z == 1) ? Kh : Vh;

    const int m0 = blockIdx.x * 128;
    const int n0 = blockIdx.y * 128;
    const int tid = threadIdx.x;
    const int w = tid >> 6, lane = tid & 63, lc = lane & 15, lq = lane >> 4;
    const int wm = w >> 1, wn = w & 1;

    __shared__ alignas(16) short As[128 * 40];
    __shared__ alignas(16) short Bs[128 * 40];

    floatx4 acc[4][4];
#pragma unroll
    for (int i = 0; i < 4; i++)
#pragma unroll
        for (int j = 0; j < 4; j++) acc[i][j] = floatx4{0.f, 0.f, 0.f, 0.f};

    for (int kt = 0; kt < DM / 32; ++kt) {
        __syncthreads();
#pragma unroll
        for (int c = 0; c < 2; ++c) {
            int chunk = c * 256 + tid;
            int row = chunk >> 2;
            int col = (chunk & 3) * 8;
            stage8f(As + row * 40 + col, X + (size_t)(m0 + row) * DM + kt * 32 + col);
            stage8f(Bs + row * 40 + col, W + (size_t)(n0 + row) * DM + kt * 32 + col);
        }
        __syncthreads();

        bf16x8 aF[4], bF[4];
#pragma unroll
        for (int i = 0; i < 4; i++)
            aF[i] = *(const bf16x8*)(As + (wm * 64 + i * 16 + lc) * 40 + lq * 8);
#pragma unroll
        for (int j = 0; j < 4; j++)
            bF[j] = *(const bf16x8*)(Bs + (wn * 64 + j * 16 + lc) * 40 + lq * 8);
#pragma unroll
        for (int i = 0; i < 4; i++)
#pragma unroll
            for (int j = 0; j < 4; j++)
                acc[i][j] = __builtin_amdgcn_mfma_f32_16x16x32_bf16(aF[i], bF[j], acc[i][j], 0, 0, 0);
    }

#pragma unroll
    for (int j = 0; j < 4; j++) {
        int n = n0 + wn * 64 + j * 16 + lc;
        float bias = Bp[n];
        int h = n >> 6, hd = n & 63;
#pragma unroll
        for (int i = 0; i < 4; i++) {
#pragma unroll
            for (int r = 0; r < 4; r++) {
                int m = m0 + wm * 64 + i * 16 + lq * 4 + r;
                int b = m >> 11, s = m & 2047;
                float val = acc[i][j][r] + bias;
                Dst[(((size_t)(b * NH + h)) * SEQ + s) * HDD + hd] = f2bf(val);
            }
        }
    }
}

// ---------------------------------------------------------------------------
// Flash attention: one block = (b,h) x 64 q-rows; each wave owns 16 q-rows.
// ctx written fp32 straight into d_out's second chunk.
// ---------------------------------------------------------------------------
__global__ __launch_bounds__(256) void attn_kernel(
    const short* __restrict__ Qh, const short* __restrict__ Kh,
    const short* __restrict__ Vh, float* __restrict__ ctxout)
{
    const int bh = blockIdx.y;
    const int tid = threadIdx.x;
    const int w = tid >> 6, lane = tid & 63, lc = lane & 15, lq = lane >> 4;
    const int qbase = blockIdx.x * 64 + w * 16;

    const short* Qp = Qh + (size_t)bh * SEQ * HDD;
    const short* Kp = Kh + (size_t)bh * SEQ * HDD;
    const short* Vp = Vh + (size_t)bh * SEQ * HDD;

    __shared__ alignas(16) short Vt[64 * 72];      // V transposed: [d][kv], stride 72
    __shared__ alignas(16) short Pl[4][16 * 72];   // per-wave P scratch: [q][kv], stride 72

    bf16x8 aQ[2];
#pragma unroll
    for (int f = 0; f < 2; ++f)
        aQ[f] = *(const bf16x8*)(Qp + (size_t)(qbase + lc) * HDD + f * 32 + lq * 8);

    float mOld[4], lSum[4];
    floatx4 accO[4];
#pragma unroll
    for (int r = 0; r < 4; r++) { mOld[r] = -1e30f; lSum[r] = 0.f; }
#pragma unroll
    for (int dt = 0; dt < 4; dt++) accO[dt] = floatx4{0.f, 0.f, 0.f, 0.f};

    for (int kt = 0; kt < SEQ / 64; ++kt) {
        const int kv0 = kt * 64;
        __syncthreads();
        // stage V transposed into LDS
#pragma unroll
        for (int c = 0; c < 2; ++c) {
            int chunk = c * 256 + tid;
            int kv = chunk >> 3;
            int d0 = (chunk & 7) * 8;
            bf16x8 vv = *(const bf16x8*)(Vp + (size_t)(kv0 + kv) * HDD + d0);
#pragma unroll
            for (int i = 0; i < 8; i++) Vt[(d0 + i) * 72 + kv] = vv[i];
        }
        __syncthreads();

        // scores for 64 kv columns: 4 tiles of 16
        floatx4 sc[4];
#pragma unroll
        for (int nt = 0; nt < 4; nt++) {
            floatx4 sv = floatx4{0.f, 0.f, 0.f, 0.f};
#pragma unroll
            for (int f = 0; f < 2; f++) {
                bf16x8 bK = *(const bf16x8*)(Kp + (size_t)(kv0 + nt * 16 + lc) * HDD + f * 32 + lq * 8);
                sv = __builtin_amdgcn_mfma_f32_16x16x32_bf16(aQ[f], bK, sv, 0, 0, 0);
            }
#pragma unroll
            for (int r = 0; r < 4; r++) sv[r] *= 0.125f;
            sc[nt] = sv;
        }

        // online softmax update (per q-row = (lq, r); kv spread over 16 lanes x 4 tiles)
        float mNew[4], alpha[4], rsum[4];
#pragma unroll
        for (int r = 0; r < 4; r++) {
            float mx = fmaxf(fmaxf(sc[0][r], sc[1][r]), fmaxf(sc[2][r], sc[3][r]));
#pragma unroll
            for (int off = 1; off < 16; off <<= 1)
                mx = fmaxf(mx, __shfl_xor(mx, off, 64));
            mNew[r] = fmaxf(mOld[r], mx);
            alpha[r] = __expf(mOld[r] - mNew[r]);
            rsum[r] = 0.f;
        }
#pragma unroll
        for (int nt = 0; nt < 4; nt++)
#pragma unroll
            for (int r = 0; r < 4; r++) {
                float p = __expf(sc[nt][r] - mNew[r]);
                sc[nt][r] = p;
                rsum[r] += p;
            }
#pragma unroll
        for (int r = 0; r < 4; r++) {
            float rs = rsum[r];
#pragma unroll
            for (int off = 1; off < 16; off <<= 1)
                rs += __shfl_xor(rs, off, 64);
            lSum[r] = lSum[r] * alpha[r] + rs;
            mOld[r] = mNew[r];
        }

        // write P (C-layout) into per-wave LDS scratch
#pragma unroll
        for (int nt = 0; nt < 4; nt++)
#pragma unroll
            for (int r = 0; r < 4; r++)
                Pl[w][(lq * 4 + r) * 72 + nt * 16 + lc] = f2bf(sc[nt][r]);

        // rescale O accumulator
#pragma unroll
        for (int dt = 0; dt < 4; dt++)
#pragma unroll
            for (int r = 0; r < 4; r++) accO[dt][r] *= alpha[r];

        __syncthreads();  // order Pl cross-lane writes vs vector read-back

        // PV: A = P (read back in A-layout), B = Vt
#pragma unroll
        for (int f = 0; f < 2; f++) {
            bf16x8 aP = *(const bf16x8*)(&Pl[w][lc * 72 + f * 32 + lq * 8]);
#pragma unroll
            for (int dt = 0; dt < 4; dt++) {
                bf16x8 bV = *(const bf16x8*)(&Vt[(dt * 16 + lc) * 72 + f * 32 + lq * 8]);
                accO[dt] = __builtin_amdgcn_mfma_f32_16x16x32_bf16(aP, bV, accO[dt], 0, 0, 0);
            }
        }
    }

    // epilogue: ctx[b,h,q,d] = O / l  (fp32)
#pragma unroll
    for (int dt = 0; dt < 4; dt++)
#pragma unroll
        for (int r = 0; r < 4; r++) {
            int qrow = qbase + lq * 4 + r;
            int d = dt * 16 + lc;
            ctxout[((size_t)bh * SEQ + qrow) * HDD + d] = accO[dt][r] / lSum[r];
        }
}

// ---------------------------------------------------------------------------
// Output projection: out = merged(ctx) @ Wo^T + bo. A gathered from the fp32
// ctx in d_out (head-split layout), out written fp32.
// ---------------------------------------------------------------------------
__global__ __launch_bounds__(256) void outproj_kernel(
    const float* __restrict__ ctxb, const float* __restrict__ wo,
    const float* __restrict__ bo, float* __restrict__ out)
{
    const int m0 = blockIdx.x * 128;
    const int n0 = blockIdx.y * 128;
    const int tid = threadIdx.x;
    const int w = tid >> 6, lane = tid & 63, lc = lane & 15, lq = lane >> 4;
    const int wm = w >> 1, wn = w & 1;

    __shared__ alignas(16) short As[128 * 40];
    __shared__ alignas(16) short Bs[128 * 40];

    floatx4 acc[4][4];
#pragma unroll
    for (int i = 0; i < 4; i++)
#pragma unroll
        for (int j = 0; j < 4; j++) acc[i][j] = floatx4{0.f, 0.f, 0.f, 0.f};

    for (int kt = 0; kt < DM / 32; ++kt) {
        __syncthreads();
#pragma unroll
        for (int c = 0; c < 2; ++c) {
            int chunk = c * 256 + tid;
            int row = chunk >> 2;
            int col = (chunk & 3) * 8;
            int m = m0 + row;
            int b = m >> 11, s = m & 2047;
            int kcol = kt * 32 + col;
            int h = kcol >> 6, hd = kcol & 63;
            stage8f(As + row * 40 + col,
                    ctxb + (((size_t)(b * NH + h)) * SEQ + s) * HDD + hd);
            stage8f(Bs + row * 40 + col, wo + (size_t)(n0 + row) * DM + kt * 32 + col);
        }
        __syncthreads();

        bf16x8 aF[4], bF[4];
#pragma unroll
        for (int i = 0; i < 4; i++)
            aF[i] = *(const bf16x8*)(As + (wm * 64 + i * 16 + lc) * 40 + lq * 8);
#pragma unroll
        for (int j = 0; j < 4; j++)
            bF[j] = *(const bf16x8*)(Bs + (wn * 64 + j * 16 + lc) * 40 + lq * 8);
#pragma unroll
        for (int i = 0; i < 4; i++)
#pragma unroll
            for (int j = 0; j < 4; j++)
                acc[i][j] = __builtin_amdgcn_mfma_f32_16x16x32_bf16(aF[i], bF[j], acc[i][j], 0, 0, 0);
    }

#pragma unroll
    for (int j = 0; j < 4; j++) {
        int n = n0 + wn * 64 + j * 16 + lc;
        float bias = bo[n];
#pragma unroll
        for (int i = 0; i < 4; i++) {
#pragma unroll
            for (int r = 0; r < 4; r++) {
                int m = m0 + wm * 64 + i * 16 + lq * 4 + r;
                out[(size_t)m * DM + n] = acc[i][j][r] + bias;
            }
        }
    }
}

extern "C" void kernel_launch(void* const* d_in, const int* in_sizes, int n_in,
                              void* d_out, int out_size, void* d_ws, size_t ws_size,
                              hipStream_t stream) {
    const float* q  = (const float*)d_in[0];
    const float* k  = (const float*)d_in[1];
    const float* v  = (const float*)d_in[2];
    const float* wq = (const float*)d_in[3];
    const float* bq = (const float*)d_in[4];
    const float* wk = (const float*)d_in[5];
    const float* bk = (const float*)d_in[6];
    const float* wv = (const float*)d_in[7];
    const float* bv = (const float*)d_in[8];
    const float* wo = (const float*)d_in[9];
    const float* bo = (const float*)d_in[10];

    float* out0 = (float*)d_out;                          // [B,S,D] fp32
    float* ctx  = out0 + (size_t)BB * SEQ * DM;           // [B,H,S,HD] fp32

    short* Qh = (short*)d_ws;
    short* Kh = Qh + (size_t)BB * NH * SEQ * HDD;
    short* Vh = Kh + (size_t)BB * NH * SEQ * HDD;

    proj_kernel<<<dim3(64, 8, 3), 256, 0, stream>>>(q, k, v, wq, bq, wk, bk, wv, bv, Qh, Kh, Vh);
    attn_kernel<<<dim3(32, 64), 256, 0, stream>>>(Qh, Kh, Vh, ctx);
    outproj_kernel<<<dim3(64, 8), 256, 0, stream>>>(ctx, wo, bo, out0);
}